// Round 1
// baseline (203.101 us; speedup 1.0000x reference)
//
#include <hip/hip_runtime.h>
#include <hip/hip_bf16.h>

#define BN_EPS 1e-5f

typedef __attribute__((ext_vector_type(8))) short bf16x8;
typedef __attribute__((ext_vector_type(4))) float f32x4;

__device__ __forceinline__ unsigned short f2bf(float f) {
    union { float f; unsigned u; } x; x.f = f;
    unsigned u = x.u;
    unsigned r = (u + 0x7fffu + ((u >> 16) & 1u)) >> 16;  // RTNE
    return (unsigned short)r;
}

// Kernel 1: z = (ghostBN(x @ W^T) * gamma + beta) * prior
// One block = 128 rows (exactly one virtual batch) x 128 cols. 256 threads = 4 waves (2x2).
__global__ __launch_bounds__(256, 2) void gemm_bn_kernel(
    const float* __restrict__ x,      // [B, K]
    const float* __restrict__ W,      // [F, K]
    const float* __restrict__ gamma,  // [F]
    const float* __restrict__ beta,   // [F]
    const float* __restrict__ prior,  // [B, F]
    float* __restrict__ z,            // [B, F]
    int B, int F, int K)
{
    const int tid  = threadIdx.x;
    const int lane = tid & 63;
    const int wid  = tid >> 6;
    const int wr   = wid >> 1;   // wave row half (0..1)
    const int wc   = wid & 1;    // wave col half (0..1)
    const int row0 = blockIdx.y * 128;
    const int col0 = blockIdx.x * 128;
    const int l15  = lane & 15;
    const int lq   = lane >> 4;  // 0..3

    __shared__ __align__(16) unsigned short As[128 * 64];
    __shared__ __align__(16) unsigned short Bs[128 * 64];
    __shared__ float red[2][128][2];

    f32x4 acc[4][4];
    const f32x4 zero = {0.f, 0.f, 0.f, 0.f};
#pragma unroll
    for (int m = 0; m < 4; ++m)
#pragma unroll
        for (int n = 0; n < 4; ++n) acc[m][n] = zero;

    for (int k0 = 0; k0 < K; k0 += 64) {
        // ---- stage A (x) and B (W) tiles: 128x64 f32 -> bf16, XOR-swizzled LDS ----
#pragma unroll
        for (int i = 0; i < 4; ++i) {
            int c = tid + i * 256;   // 0..1023 chunks of 8 elems
            int r = c >> 3;
            int s = c & 7;
            {
                const float4* pa = reinterpret_cast<const float4*>(x + (size_t)(row0 + r) * K + k0 + s * 8);
                float4 lo = pa[0], hi = pa[1];
                union { unsigned short us[8]; uint4 v; } pk;
                pk.us[0] = f2bf(lo.x); pk.us[1] = f2bf(lo.y); pk.us[2] = f2bf(lo.z); pk.us[3] = f2bf(lo.w);
                pk.us[4] = f2bf(hi.x); pk.us[5] = f2bf(hi.y); pk.us[6] = f2bf(hi.z); pk.us[7] = f2bf(hi.w);
                *reinterpret_cast<uint4*>(&As[r * 64 + ((s ^ (r & 7)) * 8)]) = pk.v;
            }
            {
                const float4* pb = reinterpret_cast<const float4*>(W + (size_t)(col0 + r) * K + k0 + s * 8);
                float4 lo = pb[0], hi = pb[1];
                union { unsigned short us[8]; uint4 v; } pk;
                pk.us[0] = f2bf(lo.x); pk.us[1] = f2bf(lo.y); pk.us[2] = f2bf(lo.z); pk.us[3] = f2bf(lo.w);
                pk.us[4] = f2bf(hi.x); pk.us[5] = f2bf(hi.y); pk.us[6] = f2bf(hi.z); pk.us[7] = f2bf(hi.w);
                *reinterpret_cast<uint4*>(&Bs[r * 64 + ((s ^ (r & 7)) * 8)]) = pk.v;
            }
        }
        __syncthreads();

        // ---- MFMA: two K=32 steps ----
#pragma unroll
        for (int ks = 0; ks < 2; ++ks) {
            bf16x8 af[4], bfr[4];
#pragma unroll
            for (int m = 0; m < 4; ++m) {
                int r = wr * 64 + m * 16 + l15;
                int s = ks * 4 + lq;
                af[m] = *reinterpret_cast<const bf16x8*>(&As[r * 64 + ((s ^ (r & 7)) * 8)]);
            }
#pragma unroll
            for (int n = 0; n < 4; ++n) {
                int r = wc * 64 + n * 16 + l15;
                int s = ks * 4 + lq;
                bfr[n] = *reinterpret_cast<const bf16x8*>(&Bs[r * 64 + ((s ^ (r & 7)) * 8)]);
            }
#pragma unroll
            for (int m = 0; m < 4; ++m)
#pragma unroll
                for (int n = 0; n < 4; ++n)
                    acc[m][n] = __builtin_amdgcn_mfma_f32_16x16x32_bf16(af[m], bfr[n], acc[m][n], 0, 0, 0);
        }
        __syncthreads();
    }

    // ---- GhostBN stats: per-column sum/sumsq over the block's 128 rows ----
    float psum[4], psq[4];
#pragma unroll
    for (int n = 0; n < 4; ++n) {
        float s = 0.f, q = 0.f;
#pragma unroll
        for (int m = 0; m < 4; ++m)
#pragma unroll
            for (int r = 0; r < 4; ++r) { float v = acc[m][n][r]; s += v; q += v * v; }
        s += __shfl_xor(s, 16); q += __shfl_xor(q, 16);
        s += __shfl_xor(s, 32); q += __shfl_xor(q, 32);
        psum[n] = s; psq[n] = q;
    }
    if (lane < 16) {
#pragma unroll
        for (int n = 0; n < 4; ++n) {
            red[wr][wc * 64 + n * 16 + lane][0] = psum[n];
            red[wr][wc * 64 + n * 16 + lane][1] = psq[n];
        }
    }
    __syncthreads();

    // ---- epilogue: BN + prior scale, write z ----
#pragma unroll
    for (int n = 0; n < 4; ++n) {
        int cl = wc * 64 + n * 16 + l15;
        int cg = col0 + cl;
        float tot = red[0][cl][0] + red[1][cl][0];
        float tsq = red[0][cl][1] + red[1][cl][1];
        float mu  = tot * (1.f / 128.f);
        float var = tsq * (1.f / 128.f) - mu * mu;
        float rv  = rsqrtf(var + BN_EPS);
        float g   = gamma[cg] * rv;
        float bt  = beta[cg] - mu * g;
#pragma unroll
        for (int m = 0; m < 4; ++m) {
#pragma unroll
            for (int r = 0; r < 4; ++r) {
                int rg = row0 + wr * 64 + m * 16 + lq * 4 + r;
                size_t idx = (size_t)rg * F + cg;
                z[idx] = (acc[m][n][r] * g + bt) * prior[idx];
            }
        }
    }
}

// Kernel 2: in-place sparsemax over each row of z (F=2048). One wave per row.
// Michelot's algorithm: tau fixed point of tau = (sum_{z>tau} z - 1)/|{z>tau}|.
__global__ __launch_bounds__(256, 4) void sparsemax_kernel(float* __restrict__ z, int B, int F)
{
    const int lane = threadIdx.x & 63;
    const int wid  = threadIdx.x >> 6;
    const int row  = blockIdx.x * 4 + wid;
    if (row >= B) return;
    float* rp = z + (size_t)row * F;

    float4 v[8];
    float s = 0.f;
#pragma unroll
    for (int j = 0; j < 8; ++j) {
        v[j] = reinterpret_cast<const float4*>(rp)[j * 64 + lane];
        s += v[j].x + v[j].y + v[j].z + v[j].w;
    }
#pragma unroll
    for (int o = 32; o; o >>= 1) s += __shfl_xor(s, o);

    float tau = (s - 1.f) / (float)F;
    int cprev = F;
    for (int it = 0; it < 64; ++it) {
        float s2 = 0.f; int c2 = 0;
#pragma unroll
        for (int j = 0; j < 8; ++j) {
            if (v[j].x > tau) { s2 += v[j].x; ++c2; }
            if (v[j].y > tau) { s2 += v[j].y; ++c2; }
            if (v[j].z > tau) { s2 += v[j].z; ++c2; }
            if (v[j].w > tau) { s2 += v[j].w; ++c2; }
        }
#pragma unroll
        for (int o = 32; o; o >>= 1) { s2 += __shfl_xor(s2, o); c2 += __shfl_xor(c2, o); }
        if (c2 == cprev) break;
        tau = (s2 - 1.f) / (float)c2;
        cprev = c2;
    }

#pragma unroll
    for (int j = 0; j < 8; ++j) {
        float4 o4;
        o4.x = fmaxf(v[j].x - tau, 0.f);
        o4.y = fmaxf(v[j].y - tau, 0.f);
        o4.z = fmaxf(v[j].z - tau, 0.f);
        o4.w = fmaxf(v[j].w - tau, 0.f);
        reinterpret_cast<float4*>(rp)[j * 64 + lane] = o4;
    }
}

extern "C" void kernel_launch(void* const* d_in, const int* in_sizes, int n_in,
                              void* d_out, int out_size, void* d_ws, size_t ws_size,
                              hipStream_t stream) {
    const float* x     = (const float*)d_in[0];
    const float* prior = (const float*)d_in[1];
    const float* W     = (const float*)d_in[2];
    const float* gamma = (const float*)d_in[3];
    const float* beta  = (const float*)d_in[4];
    float* out = (float*)d_out;

    const int F = in_sizes[3];              // 2048
    const int K = in_sizes[2] / F;          // 512
    const int B = in_sizes[0] / K;          // 16384

    dim3 g1(F / 128, B / 128);              // (16, 128)
    gemm_bn_kernel<<<g1, dim3(256), 0, stream>>>(x, W, gamma, beta, prior, out, B, F, K);
    sparsemax_kernel<<<dim3(B / 4), dim3(256), 0, stream>>>(out, B, F);
}

// Round 2
// 143.484 us; speedup vs baseline: 1.4155x; 1.4155x over previous
//
#include <hip/hip_runtime.h>
#include <hip/hip_bf16.h>

#define BN_EPS 1e-5f

typedef __attribute__((ext_vector_type(8))) short bf16x8;
typedef __attribute__((ext_vector_type(4))) float f32x4;

__device__ __forceinline__ unsigned short f2bf(float f) {
    union { float f; unsigned u; } x; x.f = f;
    unsigned u = x.u;
    unsigned r = (u + 0x7fffu + ((u >> 16) & 1u)) >> 16;  // RTNE
    return (unsigned short)r;
}

// ---------------- f32 -> bf16 pre-conversion (8 elems/thread) ----------------
__global__ __launch_bounds__(256) void cvt_bf16_kernel(
    const float* __restrict__ in, unsigned short* __restrict__ out, int n8)
{
    int i = blockIdx.x * 256 + threadIdx.x;
    if (i >= n8) return;
    const float4* p = reinterpret_cast<const float4*>(in) + (size_t)i * 2;
    float4 lo = p[0], hi = p[1];
    union { unsigned short us[8]; uint4 v; } pk;
    pk.us[0] = f2bf(lo.x); pk.us[1] = f2bf(lo.y); pk.us[2] = f2bf(lo.z); pk.us[3] = f2bf(lo.w);
    pk.us[4] = f2bf(hi.x); pk.us[5] = f2bf(hi.y); pk.us[6] = f2bf(hi.z); pk.us[7] = f2bf(hi.w);
    reinterpret_cast<uint4*>(out)[i] = pk.v;
}

// ---------------- main GEMM + ghostBN + prior-scale (bf16 inputs) ----------------
// m97 structure: 128x128 tile, BK=64, global_load_lds width=16 direct staging,
// single-buffered LDS, source-side XOR swizzle (rule #21) for conflict-free reads.
__global__ __launch_bounds__(256, 2) void gemm_bn_lds_kernel(
    const unsigned short* __restrict__ xb,  // [B, K] bf16
    const unsigned short* __restrict__ Wb,  // [F, K] bf16
    const float* __restrict__ gamma,
    const float* __restrict__ beta,
    const float* __restrict__ prior,
    float* __restrict__ z,
    int B, int F, int K)
{
    const int tid  = threadIdx.x;
    const int lane = tid & 63;
    const int wid  = tid >> 6;
    const int wr   = wid >> 1;
    const int wc   = wid & 1;
    const int row0 = blockIdx.y * 128;
    const int col0 = blockIdx.x * 128;
    const int l15  = lane & 15;
    const int lq   = lane >> 4;

    __shared__ __align__(16) unsigned short As[128 * 64];  // 16 KB
    __shared__ __align__(16) unsigned short Bs[128 * 64];  // 16 KB
    __shared__ float red[2][128][2];

    f32x4 acc[4][4];
    const f32x4 zero = {0.f, 0.f, 0.f, 0.f};
#pragma unroll
    for (int m = 0; m < 4; ++m)
#pragma unroll
        for (int n = 0; n < 4; ++n) acc[m][n] = zero;

    // chunk index for staging: c = (wid*4 + j)*64 + lane, c in [0,1024)
    // row = c>>3, s_lin = c&7 (16B chunk within row), source chunk = s_lin ^ (row&7)
    const int cbase = wid * 4 * 64 + lane;

    for (int k0 = 0; k0 < K; k0 += 64) {
#pragma unroll
        for (int j = 0; j < 4; ++j) {
            int c = cbase + j * 64;
            int row = c >> 3;
            int s_src = (c & 7) ^ (row & 7);
            unsigned ldsoff = (unsigned)(wid * 4 + j) * 1024;  // bytes, wave-uniform
            {
                const unsigned short* g = xb + (size_t)(row0 + row) * K + k0 + s_src * 8;
                __builtin_amdgcn_global_load_lds(
                    (const __attribute__((address_space(1))) void*)g,
                    (__attribute__((address_space(3))) void*)((char*)As + ldsoff),
                    16, 0, 0);
            }
            {
                const unsigned short* g = Wb + (size_t)(col0 + row) * K + k0 + s_src * 8;
                __builtin_amdgcn_global_load_lds(
                    (const __attribute__((address_space(1))) void*)g,
                    (__attribute__((address_space(3))) void*)((char*)Bs + ldsoff),
                    16, 0, 0);
            }
        }
        __syncthreads();

#pragma unroll
        for (int ks = 0; ks < 2; ++ks) {
            bf16x8 af[4], bfr[4];
#pragma unroll
            for (int m = 0; m < 4; ++m) {
                int r = wr * 64 + m * 16 + l15;
                int s = ks * 4 + lq;
                af[m] = *reinterpret_cast<const bf16x8*>(&As[r * 64 + ((s ^ (r & 7)) * 8)]);
            }
#pragma unroll
            for (int n = 0; n < 4; ++n) {
                int r = wc * 64 + n * 16 + l15;
                int s = ks * 4 + lq;
                bfr[n] = *reinterpret_cast<const bf16x8*>(&Bs[r * 64 + ((s ^ (r & 7)) * 8)]);
            }
#pragma unroll
            for (int m = 0; m < 4; ++m)
#pragma unroll
                for (int n = 0; n < 4; ++n)
                    acc[m][n] = __builtin_amdgcn_mfma_f32_16x16x32_bf16(af[m], bfr[n], acc[m][n], 0, 0, 0);
        }
        __syncthreads();
    }

    // ---- GhostBN stats: per-column sum/sumsq over this block's 128 rows ----
    float psum[4], psq[4];
#pragma unroll
    for (int n = 0; n < 4; ++n) {
        float s = 0.f, q = 0.f;
#pragma unroll
        for (int m = 0; m < 4; ++m)
#pragma unroll
            for (int r = 0; r < 4; ++r) { float v = acc[m][n][r]; s += v; q += v * v; }
        s += __shfl_xor(s, 16); q += __shfl_xor(q, 16);
        s += __shfl_xor(s, 32); q += __shfl_xor(q, 32);
        psum[n] = s; psq[n] = q;
    }
    if (lane < 16) {
#pragma unroll
        for (int n = 0; n < 4; ++n) {
            red[wr][wc * 64 + n * 16 + lane][0] = psum[n];
            red[wr][wc * 64 + n * 16 + lane][1] = psq[n];
        }
    }
    __syncthreads();

#pragma unroll
    for (int n = 0; n < 4; ++n) {
        int cl = wc * 64 + n * 16 + l15;
        int cg = col0 + cl;
        float tot = red[0][cl][0] + red[1][cl][0];
        float tsq = red[0][cl][1] + red[1][cl][1];
        float mu  = tot * (1.f / 128.f);
        float var = tsq * (1.f / 128.f) - mu * mu;
        float rv  = rsqrtf(var + BN_EPS);
        float g   = gamma[cg] * rv;
        float bt  = beta[cg] - mu * g;
#pragma unroll
        for (int m = 0; m < 4; ++m) {
#pragma unroll
            for (int r = 0; r < 4; ++r) {
                int rg = row0 + wr * 64 + m * 16 + lq * 4 + r;
                size_t idx = (size_t)rg * F + cg;
                z[idx] = (acc[m][n][r] * g + bt) * prior[idx];
            }
        }
    }
}

// ---------------- fallback (round-1): fused f32->bf16 conversion in-loop ----------------
__global__ __launch_bounds__(256, 2) void gemm_bn_kernel(
    const float* __restrict__ x, const float* __restrict__ W,
    const float* __restrict__ gamma, const float* __restrict__ beta,
    const float* __restrict__ prior, float* __restrict__ z,
    int B, int F, int K)
{
    const int tid  = threadIdx.x;
    const int lane = tid & 63;
    const int wid  = tid >> 6;
    const int wr   = wid >> 1;
    const int wc   = wid & 1;
    const int row0 = blockIdx.y * 128;
    const int col0 = blockIdx.x * 128;
    const int l15  = lane & 15;
    const int lq   = lane >> 4;

    __shared__ __align__(16) unsigned short As[128 * 64];
    __shared__ __align__(16) unsigned short Bs[128 * 64];
    __shared__ float red[2][128][2];

    f32x4 acc[4][4];
    const f32x4 zero = {0.f, 0.f, 0.f, 0.f};
#pragma unroll
    for (int m = 0; m < 4; ++m)
#pragma unroll
        for (int n = 0; n < 4; ++n) acc[m][n] = zero;

    for (int k0 = 0; k0 < K; k0 += 64) {
#pragma unroll
        for (int i = 0; i < 4; ++i) {
            int c = tid + i * 256;
            int r = c >> 3;
            int s = c & 7;
            {
                const float4* pa = reinterpret_cast<const float4*>(x + (size_t)(row0 + r) * K + k0 + s * 8);
                float4 lo = pa[0], hi = pa[1];
                union { unsigned short us[8]; uint4 v; } pk;
                pk.us[0] = f2bf(lo.x); pk.us[1] = f2bf(lo.y); pk.us[2] = f2bf(lo.z); pk.us[3] = f2bf(lo.w);
                pk.us[4] = f2bf(hi.x); pk.us[5] = f2bf(hi.y); pk.us[6] = f2bf(hi.z); pk.us[7] = f2bf(hi.w);
                *reinterpret_cast<uint4*>(&As[r * 64 + ((s ^ (r & 7)) * 8)]) = pk.v;
            }
            {
                const float4* pb = reinterpret_cast<const float4*>(W + (size_t)(col0 + r) * K + k0 + s * 8);
                float4 lo = pb[0], hi = pb[1];
                union { unsigned short us[8]; uint4 v; } pk;
                pk.us[0] = f2bf(lo.x); pk.us[1] = f2bf(lo.y); pk.us[2] = f2bf(lo.z); pk.us[3] = f2bf(lo.w);
                pk.us[4] = f2bf(hi.x); pk.us[5] = f2bf(hi.y); pk.us[6] = f2bf(hi.z); pk.us[7] = f2bf(hi.w);
                *reinterpret_cast<uint4*>(&Bs[r * 64 + ((s ^ (r & 7)) * 8)]) = pk.v;
            }
        }
        __syncthreads();
#pragma unroll
        for (int ks = 0; ks < 2; ++ks) {
            bf16x8 af[4], bfr[4];
#pragma unroll
            for (int m = 0; m < 4; ++m) {
                int r = wr * 64 + m * 16 + l15;
                int s = ks * 4 + lq;
                af[m] = *reinterpret_cast<const bf16x8*>(&As[r * 64 + ((s ^ (r & 7)) * 8)]);
            }
#pragma unroll
            for (int n = 0; n < 4; ++n) {
                int r = wc * 64 + n * 16 + l15;
                int s = ks * 4 + lq;
                bfr[n] = *reinterpret_cast<const bf16x8*>(&Bs[r * 64 + ((s ^ (r & 7)) * 8)]);
            }
#pragma unroll
            for (int m = 0; m < 4; ++m)
#pragma unroll
                for (int n = 0; n < 4; ++n)
                    acc[m][n] = __builtin_amdgcn_mfma_f32_16x16x32_bf16(af[m], bfr[n], acc[m][n], 0, 0, 0);
        }
        __syncthreads();
    }

    float psum[4], psq[4];
#pragma unroll
    for (int n = 0; n < 4; ++n) {
        float s = 0.f, q = 0.f;
#pragma unroll
        for (int m = 0; m < 4; ++m)
#pragma unroll
            for (int r = 0; r < 4; ++r) { float v = acc[m][n][r]; s += v; q += v * v; }
        s += __shfl_xor(s, 16); q += __shfl_xor(q, 16);
        s += __shfl_xor(s, 32); q += __shfl_xor(q, 32);
        psum[n] = s; psq[n] = q;
    }
    if (lane < 16) {
#pragma unroll
        for (int n = 0; n < 4; ++n) {
            red[wr][wc * 64 + n * 16 + lane][0] = psum[n];
            red[wr][wc * 64 + n * 16 + lane][1] = psq[n];
        }
    }
    __syncthreads();

#pragma unroll
    for (int n = 0; n < 4; ++n) {
        int cl = wc * 64 + n * 16 + l15;
        int cg = col0 + cl;
        float tot = red[0][cl][0] + red[1][cl][0];
        float tsq = red[0][cl][1] + red[1][cl][1];
        float mu  = tot * (1.f / 128.f);
        float var = tsq * (1.f / 128.f) - mu * mu;
        float rv  = rsqrtf(var + BN_EPS);
        float g   = gamma[cg] * rv;
        float bt  = beta[cg] - mu * g;
#pragma unroll
        for (int m = 0; m < 4; ++m) {
#pragma unroll
            for (int r = 0; r < 4; ++r) {
                int rg = row0 + wr * 64 + m * 16 + lq * 4 + r;
                size_t idx = (size_t)rg * F + cg;
                z[idx] = (acc[m][n][r] * g + bt) * prior[idx];
            }
        }
    }
}

// ---------------- sparsemax (Michelot fixed-point), one wave per row ----------------
__global__ __launch_bounds__(256, 4) void sparsemax_kernel(float* __restrict__ z, int B, int F)
{
    const int lane = threadIdx.x & 63;
    const int wid  = threadIdx.x >> 6;
    const int row  = blockIdx.x * 4 + wid;
    if (row >= B) return;
    float* rp = z + (size_t)row * F;

    float4 v[8];
    float s = 0.f;
#pragma unroll
    for (int j = 0; j < 8; ++j) {
        v[j] = reinterpret_cast<const float4*>(rp)[j * 64 + lane];
        s += v[j].x + v[j].y + v[j].z + v[j].w;
    }
#pragma unroll
    for (int o = 32; o; o >>= 1) s += __shfl_xor(s, o);

    float tau = (s - 1.f) / (float)F;
    int cprev = F;
    for (int it = 0; it < 64; ++it) {
        float s2 = 0.f; int c2 = 0;
#pragma unroll
        for (int j = 0; j < 8; ++j) {
            if (v[j].x > tau) { s2 += v[j].x; ++c2; }
            if (v[j].y > tau) { s2 += v[j].y; ++c2; }
            if (v[j].z > tau) { s2 += v[j].z; ++c2; }
            if (v[j].w > tau) { s2 += v[j].w; ++c2; }
        }
#pragma unroll
        for (int o = 32; o; o >>= 1) { s2 += __shfl_xor(s2, o); c2 += __shfl_xor(c2, o); }
        if (c2 == cprev) break;
        tau = (s2 - 1.f) / (float)c2;
        cprev = c2;
    }

#pragma unroll
    for (int j = 0; j < 8; ++j) {
        float4 o4;
        o4.x = fmaxf(v[j].x - tau, 0.f);
        o4.y = fmaxf(v[j].y - tau, 0.f);
        o4.z = fmaxf(v[j].z - tau, 0.f);
        o4.w = fmaxf(v[j].w - tau, 0.f);
        reinterpret_cast<float4*>(rp)[j * 64 + lane] = o4;
    }
}

extern "C" void kernel_launch(void* const* d_in, const int* in_sizes, int n_in,
                              void* d_out, int out_size, void* d_ws, size_t ws_size,
                              hipStream_t stream) {
    const float* x     = (const float*)d_in[0];
    const float* prior = (const float*)d_in[1];
    const float* W     = (const float*)d_in[2];
    const float* gamma = (const float*)d_in[3];
    const float* beta  = (const float*)d_in[4];
    float* out = (float*)d_out;

    const int F = in_sizes[3];              // 2048
    const int K = in_sizes[2] / F;          // 512
    const int B = in_sizes[0] / K;          // 16384

    const size_t nx = (size_t)B * K;        // x elems
    const size_t nw = (size_t)F * K;        // W elems
    const size_t need = (nx + nw) * sizeof(unsigned short);

    dim3 g1(F / 128, B / 128);
    if (ws_size >= need) {
        unsigned short* xb = (unsigned short*)d_ws;
        unsigned short* Wb = xb + nx;
        int nx8 = (int)(nx / 8), nw8 = (int)(nw / 8);
        cvt_bf16_kernel<<<dim3((nx8 + 255) / 256), dim3(256), 0, stream>>>(x, xb, nx8);
        cvt_bf16_kernel<<<dim3((nw8 + 255) / 256), dim3(256), 0, stream>>>(W, Wb, nw8);
        gemm_bn_lds_kernel<<<g1, dim3(256), 0, stream>>>(xb, Wb, gamma, beta, prior, out, B, F, K);
    } else {
        gemm_bn_kernel<<<g1, dim3(256), 0, stream>>>(x, W, gamma, beta, prior, out, B, F, K);
    }
    sparsemax_kernel<<<dim3(B / 4), dim3(256), 0, stream>>>(out, B, F);
}